// Round 1
// baseline (1157.557 us; speedup 1.0000x reference)
//
#include <hip/hip_runtime.h>
#include <math.h>

#define B_NUM 2
#define T_SEQ 2048
#define C_DIM 1024
#define H_NUM 16
#define HD    64
#define M_TOT (B_NUM * T_SEQ)   // 4096

typedef __attribute__((ext_vector_type(8))) short short8;   // 8 bf16 (4 VGPRs)
typedef __attribute__((ext_vector_type(4))) float floatx4;  // 4 fp32 acc

// fp32 -> bf16 (round-to-nearest-even), raw bits in short
__device__ __forceinline__ short f2bf(float f) {
    unsigned u = __float_as_uint(f);
    u += 0x7FFFu + ((u >> 16) & 1u);
    return (short)(u >> 16);
}

// ---------------------------------------------------------------------------
// QKV projection: out[b,h,t,d] = sum_c x[b,t,c] * W[h,c,d]
// grid: (M/64, H, 3)   block: 256 (4 waves)
// 64x64 tile, BK=32, mfma_f32_16x16x32_bf16
// ---------------------------------------------------------------------------
__global__ __launch_bounds__(256) void qkv_gemm(
    const float* __restrict__ x,
    const float* __restrict__ Wq, const float* __restrict__ Wk,
    const float* __restrict__ Wv,
    float* __restrict__ qo, float* __restrict__ ko, float* __restrict__ vo)
{
    const int mt    = blockIdx.x;
    const int h     = blockIdx.y;
    const int which = blockIdx.z;
    const float* W  = (which == 0) ? Wq : (which == 1) ? Wk : Wv;
    float* outp     = (which == 0) ? qo : (which == 1) ? ko : vo;

    const int m0 = mt * 64;
    const float* Wh = W + (size_t)h * C_DIM * HD;

    __shared__ short As[64][40];   // A tile [m][k], bf16, pad 32->40
    __shared__ short Bs[64][40];   // B tile transposed [n][k]

    const int tid  = threadIdx.x;
    const int lane = tid & 63;
    const int wv_  = tid >> 6;     // wave id 0..3
    const int lhi  = lane >> 4;    // 0..3
    const int llo  = lane & 15;    // 0..15

    floatx4 acc[4];
    for (int i = 0; i < 4; ++i)
        for (int j = 0; j < 4; ++j) acc[i][j] = 0.0f;

    for (int kt = 0; kt < C_DIM / 32; ++kt) {
        const int c0 = kt * 32;
        // stage A: 64x32 fp32 -> bf16 (coalesced float4)
        #pragma unroll
        for (int i = 0; i < 2; ++i) {
            int idx4 = tid + 256 * i;          // 512 float4
            int r    = idx4 >> 3;              // 8 float4 per row
            int c4   = idx4 & 7;
            const float4 xv = *(const float4*)(x + (size_t)(m0 + r) * C_DIM + c0 + c4 * 4);
            short4 bv;
            bv.x = f2bf(xv.x); bv.y = f2bf(xv.y); bv.z = f2bf(xv.z); bv.w = f2bf(xv.w);
            *(short4*)(&As[r][c4 * 4]) = bv;
        }
        // stage B transposed: W[h, c0+k, n] -> Bs[n][k]
        #pragma unroll
        for (int i = 0; i < 2; ++i) {
            int idx4 = tid + 256 * i;
            int kk   = idx4 >> 4;              // 16 float4 per 64-wide row
            int c4   = idx4 & 15;
            const float4 wvv = *(const float4*)(Wh + (size_t)(c0 + kk) * HD + c4 * 4);
            Bs[c4 * 4 + 0][kk] = f2bf(wvv.x);
            Bs[c4 * 4 + 1][kk] = f2bf(wvv.y);
            Bs[c4 * 4 + 2][kk] = f2bf(wvv.z);
            Bs[c4 * 4 + 3][kk] = f2bf(wvv.w);
        }
        __syncthreads();

        // A-frag: m = wv_*16 + (lane&15), k = (lane>>4)*8 + j   (contiguous)
        short8 a = *(const short8*)(&As[wv_ * 16 + llo][lhi * 8]);
        #pragma unroll
        for (int ct = 0; ct < 4; ++ct) {
            // B-frag: n = ct*16 + (lane&15), k = (lane>>4)*8 + j
            short8 b = *(const short8*)(&Bs[ct * 16 + llo][lhi * 8]);
            acc[ct] = __builtin_amdgcn_mfma_f32_16x16x32_bf16(a, b, acc[ct], 0, 0, 0);
        }
        __syncthreads();
    }

    // C/D layout: row = (lane>>4)*4 + reg, col = lane&15   [m89/m91]
    const int bidx = m0 / T_SEQ;
    const int t0   = (m0 % T_SEQ) + wv_ * 16 + lhi * 4;
    float* obase = outp + (size_t)(bidx * H_NUM + h) * T_SEQ * HD;
    #pragma unroll
    for (int ct = 0; ct < 4; ++ct) {
        const int d = ct * 16 + llo;
        #pragma unroll
        for (int r = 0; r < 4; ++r)
            obase[(size_t)(t0 + r) * HD + d] = acc[ct][r];
    }
}

// ---------------------------------------------------------------------------
// Flash attention (fp32, online softmax), causal.
// grid: (T/64, B*H)  block: 256.  Per block: one 64-row Q tile of one (b,h).
// ---------------------------------------------------------------------------
__global__ __launch_bounds__(256) void attn_fp32(
    const float* __restrict__ q, const float* __restrict__ k,
    const float* __restrict__ v, float* __restrict__ att)
{
    const int qt = blockIdx.x;     // 0..31
    const int bh = blockIdx.y;     // 0..31
    const float* Q = q + (size_t)bh * T_SEQ * HD;
    const float* K = k + (size_t)bh * T_SEQ * HD;
    const float* V = v + (size_t)bh * T_SEQ * HD;

    __shared__ float Qs[64][68];
    __shared__ float Ks[64][68];
    __shared__ float Vs[64][68];
    __shared__ float Ps[64][68];

    const int tid = threadIdx.x;
    const int tx  = tid & 15;      // S-col group / O-col group
    const int ty  = tid >> 4;      // row group
    const int i0  = ty * 4;
    const int j0  = tx * 4;

    // stage Q tile once
    #pragma unroll
    for (int i = 0; i < 4; ++i) {
        int idx4 = tid + 256 * i;
        int r    = idx4 >> 4;
        int c4   = idx4 & 15;
        *(float4*)(&Qs[r][c4 * 4]) =
            *(const float4*)(Q + (size_t)(qt * 64 + r) * HD + c4 * 4);
    }

    float  m_i[4], l_i[4];
    float4 Ov[4];
    #pragma unroll
    for (int ii = 0; ii < 4; ++ii) {
        m_i[ii] = -__builtin_inff();
        l_i[ii] = 0.0f;
        Ov[ii]  = make_float4(0.f, 0.f, 0.f, 0.f);
    }

    for (int kt = 0; kt <= qt; ++kt) {
        // stage K,V tiles
        #pragma unroll
        for (int i = 0; i < 4; ++i) {
            int idx4 = tid + 256 * i;
            int r    = idx4 >> 4;
            int c4   = idx4 & 15;
            *(float4*)(&Ks[r][c4 * 4]) =
                *(const float4*)(K + (size_t)(kt * 64 + r) * HD + c4 * 4);
            *(float4*)(&Vs[r][c4 * 4]) =
                *(const float4*)(V + (size_t)(kt * 64 + r) * HD + c4 * 4);
        }
        __syncthreads();   // also covers first-use of Qs

        // S(4x4 per thread) = Q K^T
        float s[4][4];
        #pragma unroll
        for (int ii = 0; ii < 4; ++ii)
            #pragma unroll
            for (int jj = 0; jj < 4; ++jj) s[ii][jj] = 0.f;
        for (int d4 = 0; d4 < 16; ++d4) {
            float4 qv[4], kv[4];
            #pragma unroll
            for (int ii = 0; ii < 4; ++ii) qv[ii] = *(const float4*)(&Qs[i0 + ii][d4 * 4]);
            #pragma unroll
            for (int jj = 0; jj < 4; ++jj) kv[jj] = *(const float4*)(&Ks[j0 + jj][d4 * 4]);
            #pragma unroll
            for (int ii = 0; ii < 4; ++ii)
                #pragma unroll
                for (int jj = 0; jj < 4; ++jj)
                    s[ii][jj] += qv[ii].x * kv[jj].x + qv[ii].y * kv[jj].y +
                                 qv[ii].z * kv[jj].z + qv[ii].w * kv[jj].w;
        }
        const bool diag = (kt == qt);
        #pragma unroll
        for (int ii = 0; ii < 4; ++ii)
            #pragma unroll
            for (int jj = 0; jj < 4; ++jj) {
                float val = s[ii][jj] * 0.125f;
                if (diag && (j0 + jj > i0 + ii)) val = -__builtin_inff();
                s[ii][jj] = val;
            }

        // online softmax: row stats across the 16 lanes sharing ty
        #pragma unroll
        for (int ii = 0; ii < 4; ++ii) {
            float mv = fmaxf(fmaxf(s[ii][0], s[ii][1]), fmaxf(s[ii][2], s[ii][3]));
            #pragma unroll
            for (int off = 1; off < 16; off <<= 1)
                mv = fmaxf(mv, __shfl_xor(mv, off));
            float mnew  = fmaxf(m_i[ii], mv);
            float alpha = expf(m_i[ii] - mnew);   // exp(-inf)=0 on first tile
            m_i[ii] = mnew;

            float rs = 0.f;
            #pragma unroll
            for (int jj = 0; jj < 4; ++jj) {
                float p = expf(s[ii][jj] - mnew);  // masked -inf -> 0
                s[ii][jj] = p;
                rs += p;
            }
            #pragma unroll
            for (int off = 1; off < 16; off <<= 1)
                rs += __shfl_xor(rs, off);
            l_i[ii] = l_i[ii] * alpha + rs;
            Ov[ii].x *= alpha; Ov[ii].y *= alpha; Ov[ii].z *= alpha; Ov[ii].w *= alpha;
            *(float4*)(&Ps[i0 + ii][j0]) = make_float4(s[ii][0], s[ii][1], s[ii][2], s[ii][3]);
        }
        __syncthreads();

        // O(rows i0.., d-cols tx*4..) += P * V
        for (int j4 = 0; j4 < 16; ++j4) {
            float4 vv[4];
            #pragma unroll
            for (int s2 = 0; s2 < 4; ++s2)
                vv[s2] = *(const float4*)(&Vs[j4 * 4 + s2][tx * 4]);
            #pragma unroll
            for (int ii = 0; ii < 4; ++ii) {
                float4 p4 = *(const float4*)(&Ps[i0 + ii][j4 * 4]);
                Ov[ii].x += p4.x * vv[0].x + p4.y * vv[1].x + p4.z * vv[2].x + p4.w * vv[3].x;
                Ov[ii].y += p4.x * vv[0].y + p4.y * vv[1].y + p4.z * vv[2].y + p4.w * vv[3].y;
                Ov[ii].z += p4.x * vv[0].z + p4.y * vv[1].z + p4.z * vv[2].z + p4.w * vv[3].z;
                Ov[ii].w += p4.x * vv[0].w + p4.y * vv[1].w + p4.z * vv[2].w + p4.w * vv[3].w;
            }
        }
        __syncthreads();
    }

    // write att[b, t, h*64 + d] (concat-head layout for the output GEMM)
    const int b = bh >> 4;
    const int h = bh & 15;
    #pragma unroll
    for (int ii = 0; ii < 4; ++ii) {
        float inv = 1.0f / l_i[ii];
        int t = qt * 64 + i0 + ii;
        float4 o = make_float4(Ov[ii].x * inv, Ov[ii].y * inv, Ov[ii].z * inv, Ov[ii].w * inv);
        *(float4*)(att + (size_t)(b * T_SEQ + t) * C_DIM + h * HD + tx * 4) = o;
    }
}

// ---------------------------------------------------------------------------
// Output projection: out = att @ Wp + bp
// grid: (M/64, C/64)  block: 256
// ---------------------------------------------------------------------------
__global__ __launch_bounds__(256) void proj_gemm(
    const float* __restrict__ A, const float* __restrict__ Wp,
    const float* __restrict__ bp, float* __restrict__ out)
{
    const int mt = blockIdx.x;
    const int nt = blockIdx.y;
    const int m0 = mt * 64;
    const int n0 = nt * 64;

    __shared__ short As[64][40];
    __shared__ short Bs[64][40];

    const int tid  = threadIdx.x;
    const int lane = tid & 63;
    const int wv_  = tid >> 6;
    const int lhi  = lane >> 4;
    const int llo  = lane & 15;

    floatx4 acc[4];
    for (int i = 0; i < 4; ++i)
        for (int j = 0; j < 4; ++j) acc[i][j] = 0.0f;

    for (int kt = 0; kt < C_DIM / 32; ++kt) {
        const int c0 = kt * 32;
        #pragma unroll
        for (int i = 0; i < 2; ++i) {
            int idx4 = tid + 256 * i;
            int r    = idx4 >> 3;
            int c4   = idx4 & 7;
            const float4 xv = *(const float4*)(A + (size_t)(m0 + r) * C_DIM + c0 + c4 * 4);
            short4 bv;
            bv.x = f2bf(xv.x); bv.y = f2bf(xv.y); bv.z = f2bf(xv.z); bv.w = f2bf(xv.w);
            *(short4*)(&As[r][c4 * 4]) = bv;
        }
        #pragma unroll
        for (int i = 0; i < 2; ++i) {
            int idx4 = tid + 256 * i;
            int kk   = idx4 >> 4;
            int c4   = idx4 & 15;
            const float4 wvv = *(const float4*)(Wp + (size_t)(c0 + kk) * C_DIM + n0 + c4 * 4);
            Bs[c4 * 4 + 0][kk] = f2bf(wvv.x);
            Bs[c4 * 4 + 1][kk] = f2bf(wvv.y);
            Bs[c4 * 4 + 2][kk] = f2bf(wvv.z);
            Bs[c4 * 4 + 3][kk] = f2bf(wvv.w);
        }
        __syncthreads();

        short8 a = *(const short8*)(&As[wv_ * 16 + llo][lhi * 8]);
        #pragma unroll
        for (int ct = 0; ct < 4; ++ct) {
            short8 b = *(const short8*)(&Bs[ct * 16 + llo][lhi * 8]);
            acc[ct] = __builtin_amdgcn_mfma_f32_16x16x32_bf16(a, b, acc[ct], 0, 0, 0);
        }
        __syncthreads();
    }

    #pragma unroll
    for (int ct = 0; ct < 4; ++ct) {
        const int n = n0 + ct * 16 + llo;
        const float bias = bp[n];
        #pragma unroll
        for (int r = 0; r < 4; ++r) {
            int m = m0 + wv_ * 16 + lhi * 4 + r;
            out[(size_t)m * C_DIM + n] = acc[ct][r] + bias;
        }
    }
}

// ---------------------------------------------------------------------------
extern "C" void kernel_launch(void* const* d_in, const int* in_sizes, int n_in,
                              void* d_out, int out_size, void* d_ws, size_t ws_size,
                              hipStream_t stream) {
    const float* x  = (const float*)d_in[0];
    const float* Wq = (const float*)d_in[1];
    const float* Wk = (const float*)d_in[2];
    const float* Wv = (const float*)d_in[3];
    const float* Wp = (const float*)d_in[4];
    const float* bp = (const float*)d_in[5];
    float* out = (float*)d_out;

    const size_t sz = (size_t)M_TOT * C_DIM;   // 4096*1024 floats = 16 MB each
    float* qb   = (float*)d_ws;                // [B*H, T, 64]
    float* kb   = qb + sz;
    float* vb   = kb + sz;
    float* attb = vb + sz;                     // [B, T, C]

    qkv_gemm<<<dim3(M_TOT / 64, H_NUM, 3), 256, 0, stream>>>(x, Wq, Wk, Wv, qb, kb, vb);
    attn_fp32<<<dim3(T_SEQ / 64, B_NUM * H_NUM), 256, 0, stream>>>(qb, kb, vb, attb);
    proj_gemm<<<dim3(M_TOT / 64, C_DIM / 64), 256, 0, stream>>>(attb, Wp, bp, out);
}

// Round 2
// 221.966 us; speedup vs baseline: 5.2150x; 5.2150x over previous
//
#include <hip/hip_runtime.h>

#define B_NUM 2
#define T_SEQ 2048
#define C_DIM 1024
#define H_NUM 16
#define HD    64
#define M_TOT 4096
#define BH_N  32

typedef __attribute__((ext_vector_type(8))) short short8;   // 8 bf16
typedef __attribute__((ext_vector_type(4))) float floatx4;  // 4 fp32 acc

__device__ __forceinline__ short f2bf(float f) {
    unsigned u = __float_as_uint(f);
    u += 0x7FFFu + ((u >> 16) & 1u);
    return (short)(u >> 16);
}

// ---------------------------------------------------------------------------
// x fp32 -> bf16, elementwise. grid 2048 x 256, 8 elems/thread.
// ---------------------------------------------------------------------------
__global__ __launch_bounds__(256) void convert_x(const float* __restrict__ x,
                                                 short* __restrict__ xb) {
    int idx = (blockIdx.x * 256 + threadIdx.x) * 8;
    float4 a = *(const float4*)(x + idx);
    float4 b = *(const float4*)(x + idx + 4);
    short8 o;
    o[0] = f2bf(a.x); o[1] = f2bf(a.y); o[2] = f2bf(a.z); o[3] = f2bf(a.w);
    o[4] = f2bf(b.x); o[5] = f2bf(b.y); o[6] = f2bf(b.z); o[7] = f2bf(b.w);
    *(short8*)(xb + idx) = o;
}

// ---------------------------------------------------------------------------
// Wq/Wk/Wv [h][c][d] fp32 -> Wt [which][h][d][c] bf16. grid (16, 48).
// ---------------------------------------------------------------------------
__global__ __launch_bounds__(256) void transp_wqkv(
    const float* __restrict__ Wq, const float* __restrict__ Wk,
    const float* __restrict__ Wv, short* __restrict__ wt) {
    const int ct = blockIdx.x, y = blockIdx.y;
    const int which = y >> 4, h = y & 15;
    const float* W = ((which == 0) ? Wq : (which == 1) ? Wk : Wv) + (size_t)h * C_DIM * HD;
    __shared__ short sh[64][72];
    const int tid = threadIdx.x;
    const int c0 = ct * 64;
    #pragma unroll
    for (int p = 0; p < 4; ++p) {
        int idx = tid + 256 * p;            // 1024 float4: c(64) x d4(16)
        int c = idx >> 4, d4 = idx & 15;
        float4 v = *(const float4*)(W + (size_t)(c0 + c) * HD + d4 * 4);
        sh[d4 * 4 + 0][c] = f2bf(v.x);
        sh[d4 * 4 + 1][c] = f2bf(v.y);
        sh[d4 * 4 + 2][c] = f2bf(v.z);
        sh[d4 * 4 + 3][c] = f2bf(v.w);
    }
    __syncthreads();
    #pragma unroll
    for (int p = 0; p < 2; ++p) {
        int idx = tid + 256 * p;            // 512 chunks: d(64) x cc(8)
        int d = idx >> 3, cc = idx & 7;
        short8 vv = *(const short8*)(&sh[d][cc * 8]);
        *(short8*)(wt + ((size_t)(which * 16 + h) * 64 + d) * C_DIM + c0 + cc * 8) = vv;
    }
}

// ---------------------------------------------------------------------------
// Wp [k][n] fp32 -> Wpt [n][k] bf16. grid (16, 16).
// ---------------------------------------------------------------------------
__global__ __launch_bounds__(256) void transp_wp(const float* __restrict__ Wp,
                                                 short* __restrict__ wpt) {
    const int ct = blockIdx.x, nt = blockIdx.y;
    __shared__ short sh[64][72];
    const int tid = threadIdx.x;
    #pragma unroll
    for (int p = 0; p < 4; ++p) {
        int idx = tid + 256 * p;
        int k = idx >> 4, n4 = idx & 15;
        float4 v = *(const float4*)(Wp + (size_t)(ct * 64 + k) * C_DIM + nt * 64 + n4 * 4);
        sh[n4 * 4 + 0][k] = f2bf(v.x);
        sh[n4 * 4 + 1][k] = f2bf(v.y);
        sh[n4 * 4 + 2][k] = f2bf(v.z);
        sh[n4 * 4 + 3][k] = f2bf(v.w);
    }
    __syncthreads();
    #pragma unroll
    for (int p = 0; p < 2; ++p) {
        int idx = tid + 256 * p;
        int n = idx >> 3, cc = idx & 7;
        short8 vv = *(const short8*)(&sh[n][cc * 8]);
        *(short8*)(wpt + (size_t)(nt * 64 + n) * C_DIM + ct * 64 + cc * 8) = vv;
    }
}

// ---------------------------------------------------------------------------
// V [bh][T][64] bf16 -> Vt [bh][64][T] bf16. grid (32, 32).
// ---------------------------------------------------------------------------
__global__ __launch_bounds__(256) void transp_v(const short* __restrict__ vb,
                                                short* __restrict__ vtb) {
    const int tt = blockIdx.x, bh = blockIdx.y;
    __shared__ short sh[64][72];
    const int tid = threadIdx.x;
    #pragma unroll
    for (int p = 0; p < 2; ++p) {
        int idx = tid + 256 * p;            // 512 chunks: t(64) x cc(8)
        int t = idx >> 3, cc = idx & 7;
        short8 s8 = *(const short8*)(vb + ((size_t)bh * T_SEQ + tt * 64 + t) * HD + cc * 8);
        #pragma unroll
        for (int j = 0; j < 8; ++j) sh[cc * 8 + j][t] = s8[j];
    }
    __syncthreads();
    #pragma unroll
    for (int p = 0; p < 2; ++p) {
        int idx = tid + 256 * p;
        int d = idx >> 3, cc = idx & 7;
        short8 vv = *(const short8*)(&sh[d][cc * 8]);
        *(short8*)(vtb + ((size_t)bh * HD + d) * T_SEQ + tt * 64 + cc * 8) = vv;
    }
}

// ---------------------------------------------------------------------------
// QKV GEMM, bf16 in/out: out[bh][t][d] = sum_c xb[t][c] * W[h][c][d]
// grid (32, 16, 3), block 256. Tile 128(m) x 64(n), BK=64.
// Q output pre-scaled by 0.125*log2(e) for exp2-domain softmax.
// ---------------------------------------------------------------------------
__global__ __launch_bounds__(256) void qkv_gemm(
    const short* __restrict__ xb, const short* __restrict__ wt,
    short* __restrict__ qb, short* __restrict__ kb, short* __restrict__ vb) {
    const int mt = blockIdx.x, h = blockIdx.y, which = blockIdx.z;
    short* outp = (which == 0) ? qb : (which == 1) ? kb : vb;
    const float sc = (which == 0) ? 0.125f * 1.4426950408889634f : 1.0f;
    const short* W = wt + (size_t)(which * 16 + h) * 64 * C_DIM;   // [d][c]
    const int m0 = mt * 128;

    __shared__ short As[128][72];   // [m][k]
    __shared__ short Bst[64][72];   // [n=d][k=c]

    const int tid = threadIdx.x;
    const int lane = tid & 63, w = tid >> 6;
    const int hi = lane >> 4, llo = lane & 15;

    floatx4 acc[2][4];
    #pragma unroll
    for (int i = 0; i < 2; ++i)
        #pragma unroll
        for (int j = 0; j < 4; ++j)
            #pragma unroll
            for (int r = 0; r < 4; ++r) acc[i][j][r] = 0.0f;

    for (int kt = 0; kt < C_DIM / 64; ++kt) {
        const int c0 = kt * 64;
        #pragma unroll
        for (int p = 0; p < 4; ++p) {       // A: 128 rows x 8 chunks
            int idx = tid + 256 * p;
            int r = idx >> 3, cc = idx & 7;
            *(short8*)(&As[r][cc * 8]) =
                *(const short8*)(xb + (size_t)(m0 + r) * C_DIM + c0 + cc * 8);
        }
        #pragma unroll
        for (int p = 0; p < 2; ++p) {       // B: 64 rows x 8 chunks
            int idx = tid + 256 * p;
            int d = idx >> 3, cc = idx & 7;
            *(short8*)(&Bst[d][cc * 8]) =
                *(const short8*)(W + (size_t)d * C_DIM + c0 + cc * 8);
        }
        __syncthreads();

        short8 af[2][2];
        #pragma unroll
        for (int m2 = 0; m2 < 2; ++m2)
            #pragma unroll
            for (int kh = 0; kh < 2; ++kh)
                af[m2][kh] = *(const short8*)(&As[w * 32 + m2 * 16 + llo][kh * 32 + hi * 8]);
        #pragma unroll
        for (int nt = 0; nt < 4; ++nt)
            #pragma unroll
            for (int kh = 0; kh < 2; ++kh) {
                short8 bf = *(const short8*)(&Bst[nt * 16 + llo][kh * 32 + hi * 8]);
                #pragma unroll
                for (int m2 = 0; m2 < 2; ++m2)
                    acc[m2][nt] = __builtin_amdgcn_mfma_f32_16x16x32_bf16(
                        af[m2][kh], bf, acc[m2][nt], 0, 0, 0);
            }
        __syncthreads();
    }

    // epilogue: bf16 via LDS (reuse As), then vector copy-out
    #pragma unroll
    for (int m2 = 0; m2 < 2; ++m2)
        #pragma unroll
        for (int nt = 0; nt < 4; ++nt)
            #pragma unroll
            for (int r = 0; r < 4; ++r)
                As[w * 32 + m2 * 16 + hi * 4 + r][nt * 16 + llo] = f2bf(acc[m2][nt][r] * sc);
    __syncthreads();
    #pragma unroll
    for (int p = 0; p < 4; ++p) {
        int idx = tid + 256 * p;            // 1024 chunks: r(128) x cc(8)
        int r = idx >> 3, cc = idx & 7;
        short8 vv = *(const short8*)(&As[r][cc * 8]);
        int mg = m0 + r;
        int b = mg >> 11, t = mg & 2047;
        *(short8*)(outp + ((size_t)(b * H_NUM + h) * T_SEQ + t) * HD + cc * 8) = vv;
    }
}

// ---------------------------------------------------------------------------
// Flash attention, bf16 MFMA, exp2-domain online softmax.
// grid (16, 32): block handles q-tiles {x, 31-x} of head y -> constant work.
// ---------------------------------------------------------------------------
__global__ __launch_bounds__(256) void attn_mfma(
    const short* __restrict__ qb, const short* __restrict__ kb,
    const short* __restrict__ vtb, short* __restrict__ attb) {
    const int bh = blockIdx.y;
    const int b = bh >> 4, h = bh & 15;
    const short* K  = kb  + (size_t)bh * T_SEQ * HD;    // [s][d]
    const short* Vt = vtb + (size_t)bh * HD * T_SEQ;    // [d][s]

    __shared__ short Qs[64][72];
    __shared__ short Ks[64][72];
    __shared__ short Vts[64][72];
    __shared__ short Ps[64][72];

    const int tid = threadIdx.x;
    const int lane = tid & 63, w = tid >> 6;
    const int hi = lane >> 4, llo = lane & 15;

    for (int qpass = 0; qpass < 2; ++qpass) {
        const int qt = qpass ? (31 - blockIdx.x) : blockIdx.x;
        const short* Q = qb + ((size_t)bh * T_SEQ + qt * 64) * HD;

        // stage Q tile
        #pragma unroll
        for (int p = 0; p < 2; ++p) {
            int idx = tid + 256 * p;
            int r = idx >> 3, cc = idx & 7;
            *(short8*)(&Qs[r][cc * 8]) = *(const short8*)(Q + (size_t)r * HD + cc * 8);
        }

        float mrow[4], lrow[4];
        floatx4 Oa[4];
        #pragma unroll
        for (int r = 0; r < 4; ++r) { mrow[r] = -3.0e38f; lrow[r] = 0.0f; }
        #pragma unroll
        for (int nt = 0; nt < 4; ++nt)
            #pragma unroll
            for (int r = 0; r < 4; ++r) Oa[nt][r] = 0.0f;

        for (int kt = 0; kt <= qt; ++kt) {
            // stage K and Vt tiles
            #pragma unroll
            for (int p = 0; p < 2; ++p) {
                int idx = tid + 256 * p;
                int r = idx >> 3, cc = idx & 7;
                *(short8*)(&Ks[r][cc * 8]) =
                    *(const short8*)(K + ((size_t)kt * 64 + r) * HD + cc * 8);
            }
            #pragma unroll
            for (int p = 0; p < 2; ++p) {
                int idx = tid + 256 * p;
                int r = idx >> 3, cc = idx & 7;
                *(short8*)(&Vts[r][cc * 8]) =
                    *(const short8*)(Vt + (size_t)r * T_SEQ + kt * 64 + cc * 8);
            }
            __syncthreads();

            // S = Q K^T  (wave w owns rows w*16..w*16+15)
            short8 aq[2];
            #pragma unroll
            for (int kh = 0; kh < 2; ++kh)
                aq[kh] = *(const short8*)(&Qs[w * 16 + llo][kh * 32 + hi * 8]);
            floatx4 sf[4];
            #pragma unroll
            for (int nt = 0; nt < 4; ++nt)
                #pragma unroll
                for (int r = 0; r < 4; ++r) sf[nt][r] = 0.0f;
            #pragma unroll
            for (int nt = 0; nt < 4; ++nt)
                #pragma unroll
                for (int kh = 0; kh < 2; ++kh) {
                    short8 bk = *(const short8*)(&Ks[nt * 16 + llo][kh * 32 + hi * 8]);
                    sf[nt] = __builtin_amdgcn_mfma_f32_16x16x32_bf16(aq[kh], bk, sf[nt], 0, 0, 0);
                }

            // causal mask on diagonal tile
            if (kt == qt) {
                const int rbase = w * 16 + hi * 4;
                #pragma unroll
                for (int nt = 0; nt < 4; ++nt)
                    #pragma unroll
                    for (int r = 0; r < 4; ++r)
                        if (nt * 16 + llo > rbase + r) sf[nt][r] = -3.0e38f;
            }

            // online softmax (exp2 domain; scale folded into Q)
            float alpha[4], rs[4];
            #pragma unroll
            for (int r = 0; r < 4; ++r) {
                float rm = fmaxf(fmaxf(sf[0][r], sf[1][r]), fmaxf(sf[2][r], sf[3][r]));
                #pragma unroll
                for (int off = 1; off < 16; off <<= 1)
                    rm = fmaxf(rm, __shfl_xor(rm, off));
                float mn = fmaxf(mrow[r], rm);
                alpha[r] = __builtin_amdgcn_exp2f(mrow[r] - mn);
                mrow[r] = mn;
                rs[r] = 0.0f;
            }
            #pragma unroll
            for (int nt = 0; nt < 4; ++nt)
                #pragma unroll
                for (int r = 0; r < 4; ++r) {
                    float pp = __builtin_amdgcn_exp2f(sf[nt][r] - mrow[r]);
                    sf[nt][r] = pp;
                    rs[r] += pp;
                }
            #pragma unroll
            for (int r = 0; r < 4; ++r) {
                #pragma unroll
                for (int off = 1; off < 16; off <<= 1)
                    rs[r] += __shfl_xor(rs[r], off);
                lrow[r] = lrow[r] * alpha[r] + rs[r];
            }
            #pragma unroll
            for (int nt = 0; nt < 4; ++nt)
                #pragma unroll
                for (int r = 0; r < 4; ++r) Oa[nt][r] *= alpha[r];

            // P (C-layout) -> LDS bf16 (A-layout source)
            #pragma unroll
            for (int nt = 0; nt < 4; ++nt)
                #pragma unroll
                for (int r = 0; r < 4; ++r)
                    Ps[w * 16 + hi * 4 + r][nt * 16 + llo] = f2bf(sf[nt][r]);

            // O += P V
            short8 ap[2];
            #pragma unroll
            for (int kh = 0; kh < 2; ++kh)
                ap[kh] = *(const short8*)(&Ps[w * 16 + llo][kh * 32 + hi * 8]);
            #pragma unroll
            for (int nt = 0; nt < 4; ++nt)
                #pragma unroll
                for (int kh = 0; kh < 2; ++kh) {
                    short8 bv = *(const short8*)(&Vts[nt * 16 + llo][kh * 32 + hi * 8]);
                    Oa[nt] = __builtin_amdgcn_mfma_f32_16x16x32_bf16(ap[kh], bv, Oa[nt], 0, 0, 0);
                }
            __syncthreads();
        }

        // epilogue: O/l -> bf16 via Ps, vector copy to att[b][t][h*64+d]
        #pragma unroll
        for (int nt = 0; nt < 4; ++nt)
            #pragma unroll
            for (int r = 0; r < 4; ++r)
                Ps[w * 16 + hi * 4 + r][nt * 16 + llo] = f2bf(Oa[nt][r] / lrow[r]);
        __syncthreads();
        #pragma unroll
        for (int p = 0; p < 2; ++p) {
            int idx = tid + 256 * p;
            int r = idx >> 3, cc = idx & 7;
            short8 vv = *(const short8*)(&Ps[r][cc * 8]);
            *(short8*)(attb + ((size_t)(b * T_SEQ + qt * 64 + r)) * C_DIM + h * HD + cc * 8) = vv;
        }
        __syncthreads();
    }
}

// ---------------------------------------------------------------------------
// Output projection: out = att(bf16) @ Wp + bp, fp32 out.
// grid (32, 16), block 256. Tile 128 x 64, BK=64. B from Wpt [n][k].
// ---------------------------------------------------------------------------
__global__ __launch_bounds__(256) void proj_gemm(
    const short* __restrict__ attb, const short* __restrict__ wpt,
    const float* __restrict__ bp, float* __restrict__ out) {
    const int mt = blockIdx.x, nt_g = blockIdx.y;
    const int m0 = mt * 128, n0 = nt_g * 64;

    __shared__ short As[128][72];
    __shared__ short Bst[64][72];

    const int tid = threadIdx.x;
    const int lane = tid & 63, w = tid >> 6;
    const int hi = lane >> 4, llo = lane & 15;

    floatx4 acc[2][4];
    #pragma unroll
    for (int i = 0; i < 2; ++i)
        #pragma unroll
        for (int j = 0; j < 4; ++j)
            #pragma unroll
            for (int r = 0; r < 4; ++r) acc[i][j][r] = 0.0f;

    for (int kt = 0; kt < C_DIM / 64; ++kt) {
        const int c0 = kt * 64;
        #pragma unroll
        for (int p = 0; p < 4; ++p) {
            int idx = tid + 256 * p;
            int r = idx >> 3, cc = idx & 7;
            *(short8*)(&As[r][cc * 8]) =
                *(const short8*)(attb + (size_t)(m0 + r) * C_DIM + c0 + cc * 8);
        }
        #pragma unroll
        for (int p = 0; p < 2; ++p) {
            int idx = tid + 256 * p;
            int n = idx >> 3, cc = idx & 7;
            *(short8*)(&Bst[n][cc * 8]) =
                *(const short8*)(wpt + (size_t)(n0 + n) * C_DIM + c0 + cc * 8);
        }
        __syncthreads();

        short8 af[2][2];
        #pragma unroll
        for (int m2 = 0; m2 < 2; ++m2)
            #pragma unroll
            for (int kh = 0; kh < 2; ++kh)
                af[m2][kh] = *(const short8*)(&As[w * 32 + m2 * 16 + llo][kh * 32 + hi * 8]);
        #pragma unroll
        for (int nt = 0; nt < 4; ++nt)
            #pragma unroll
            for (int kh = 0; kh < 2; ++kh) {
                short8 bf = *(const short8*)(&Bst[nt * 16 + llo][kh * 32 + hi * 8]);
                #pragma unroll
                for (int m2 = 0; m2 < 2; ++m2)
                    acc[m2][nt] = __builtin_amdgcn_mfma_f32_16x16x32_bf16(
                        af[m2][kh], bf, acc[m2][nt], 0, 0, 0);
            }
        __syncthreads();
    }

    #pragma unroll
    for (int nt = 0; nt < 4; ++nt) {
        const int n = n0 + nt * 16 + llo;
        const float bias = bp[n];
        #pragma unroll
        for (int m2 = 0; m2 < 2; ++m2)
            #pragma unroll
            for (int r = 0; r < 4; ++r) {
                int m = m0 + w * 32 + m2 * 16 + hi * 4 + r;
                out[(size_t)m * C_DIM + n] = acc[m2][nt][r] + bias;
            }
    }
}

// ---------------------------------------------------------------------------
extern "C" void kernel_launch(void* const* d_in, const int* in_sizes, int n_in,
                              void* d_out, int out_size, void* d_ws, size_t ws_size,
                              hipStream_t stream) {
    const float* x  = (const float*)d_in[0];
    const float* Wq = (const float*)d_in[1];
    const float* Wk = (const float*)d_in[2];
    const float* Wv = (const float*)d_in[3];
    const float* Wp = (const float*)d_in[4];
    const float* bp = (const float*)d_in[5];
    float* out = (float*)d_out;

    short* xb   = (short*)d_ws;                       // 4M shorts
    short* wt   = xb  + (size_t)M_TOT * C_DIM;        // 3*16*64*1024 = 3M
    short* wpt  = wt  + (size_t)3 * H_NUM * HD * C_DIM;  // 1M
    short* qb   = wpt + (size_t)C_DIM * C_DIM;        // 4M each
    short* kb   = qb  + (size_t)M_TOT * C_DIM;
    short* vb   = kb  + (size_t)M_TOT * C_DIM;
    short* vtb  = vb  + (size_t)M_TOT * C_DIM;
    short* attb = vtb + (size_t)M_TOT * C_DIM;

    convert_x  <<<dim3(M_TOT * C_DIM / 2048), 256, 0, stream>>>(x, xb);
    transp_wqkv<<<dim3(16, 48), 256, 0, stream>>>(Wq, Wk, Wv, wt);
    transp_wp  <<<dim3(16, 16), 256, 0, stream>>>(Wp, wpt);
    qkv_gemm   <<<dim3(M_TOT / 128, H_NUM, 3), 256, 0, stream>>>(xb, wt, qb, kb, vb);
    transp_v   <<<dim3(T_SEQ / 64, BH_N), 256, 0, stream>>>(vb, vtb);
    attn_mfma  <<<dim3(16, BH_N), 256, 0, stream>>>(qb, kb, vtb, attb);
    proj_gemm  <<<dim3(M_TOT / 128, C_DIM / 64), 256, 0, stream>>>(attb, wpt, bp, out);
}

// Round 3
// 220.042 us; speedup vs baseline: 5.2606x; 1.0087x over previous
//
#include <hip/hip_runtime.h>

#define B_NUM 2
#define T_SEQ 2048
#define C_DIM 1024
#define H_NUM 16
#define HD    64
#define M_TOT 4096
#define BH_N  32

typedef __attribute__((ext_vector_type(8))) short short8;   // 8 bf16
typedef __attribute__((ext_vector_type(4))) float floatx4;  // 4 fp32 acc

__device__ __forceinline__ short f2bf(float f) {
    unsigned u = __float_as_uint(f);
    u += 0x7FFFu + ((u >> 16) & 1u);
    return (short)(u >> 16);
}

// ---------------------------------------------------------------------------
// x fp32 -> bf16, elementwise.
// ---------------------------------------------------------------------------
__global__ __launch_bounds__(256) void convert_x(const float* __restrict__ x,
                                                 short* __restrict__ xb) {
    int idx = (blockIdx.x * 256 + threadIdx.x) * 8;
    float4 a = *(const float4*)(x + idx);
    float4 b = *(const float4*)(x + idx + 4);
    short8 o;
    o[0] = f2bf(a.x); o[1] = f2bf(a.y); o[2] = f2bf(a.z); o[3] = f2bf(a.w);
    o[4] = f2bf(b.x); o[5] = f2bf(b.y); o[6] = f2bf(b.z); o[7] = f2bf(b.w);
    *(short8*)(xb + idx) = o;
}

// ---------------------------------------------------------------------------
// Wq/Wk/Wv [h][c][d] fp32 -> Wt [which][h][d][c] bf16  (= flat [3072][1024]).
// ---------------------------------------------------------------------------
__global__ __launch_bounds__(256) void transp_wqkv(
    const float* __restrict__ Wq, const float* __restrict__ Wk,
    const float* __restrict__ Wv, short* __restrict__ wt) {
    const int ct = blockIdx.x, y = blockIdx.y;
    const int which = y >> 4, h = y & 15;
    const float* W = ((which == 0) ? Wq : (which == 1) ? Wk : Wv) + (size_t)h * C_DIM * HD;
    __shared__ short sh[64][72];
    const int tid = threadIdx.x;
    const int c0 = ct * 64;
    #pragma unroll
    for (int p = 0; p < 4; ++p) {
        int idx = tid + 256 * p;
        int c = idx >> 4, d4 = idx & 15;
        float4 v = *(const float4*)(W + (size_t)(c0 + c) * HD + d4 * 4);
        sh[d4 * 4 + 0][c] = f2bf(v.x);
        sh[d4 * 4 + 1][c] = f2bf(v.y);
        sh[d4 * 4 + 2][c] = f2bf(v.z);
        sh[d4 * 4 + 3][c] = f2bf(v.w);
    }
    __syncthreads();
    #pragma unroll
    for (int p = 0; p < 2; ++p) {
        int idx = tid + 256 * p;
        int d = idx >> 3, cc = idx & 7;
        short8 vv = *(const short8*)(&sh[d][cc * 8]);
        *(short8*)(wt + ((size_t)(which * 16 + h) * 64 + d) * C_DIM + c0 + cc * 8) = vv;
    }
}

// ---------------------------------------------------------------------------
// Wp [k][n] fp32 -> Wpt [n][k] bf16.
// ---------------------------------------------------------------------------
__global__ __launch_bounds__(256) void transp_wp(const float* __restrict__ Wp,
                                                 short* __restrict__ wpt) {
    const int ct = blockIdx.x, nt = blockIdx.y;
    __shared__ short sh[64][72];
    const int tid = threadIdx.x;
    #pragma unroll
    for (int p = 0; p < 4; ++p) {
        int idx = tid + 256 * p;
        int k = idx >> 4, n4 = idx & 15;
        float4 v = *(const float4*)(Wp + (size_t)(ct * 64 + k) * C_DIM + nt * 64 + n4 * 4);
        sh[n4 * 4 + 0][k] = f2bf(v.x);
        sh[n4 * 4 + 1][k] = f2bf(v.y);
        sh[n4 * 4 + 2][k] = f2bf(v.z);
        sh[n4 * 4 + 3][k] = f2bf(v.w);
    }
    __syncthreads();
    #pragma unroll
    for (int p = 0; p < 2; ++p) {
        int idx = tid + 256 * p;
        int n = idx >> 3, cc = idx & 7;
        short8 vv = *(const short8*)(&sh[n][cc * 8]);
        *(short8*)(wpt + (size_t)(nt * 64 + n) * C_DIM + ct * 64 + cc * 8) = vv;
    }
}

// ---------------------------------------------------------------------------
// V [bh][T][64] bf16 -> Vt [bh][64][T] bf16.
// ---------------------------------------------------------------------------
__global__ __launch_bounds__(256) void transp_v(const short* __restrict__ vb,
                                                short* __restrict__ vtb) {
    const int tt = blockIdx.x, bh = blockIdx.y;
    __shared__ short sh[64][72];
    const int tid = threadIdx.x;
    #pragma unroll
    for (int p = 0; p < 2; ++p) {
        int idx = tid + 256 * p;
        int t = idx >> 3, cc = idx & 7;
        short8 s8 = *(const short8*)(vb + ((size_t)bh * T_SEQ + tt * 64 + t) * HD + cc * 8);
        #pragma unroll
        for (int j = 0; j < 8; ++j) sh[cc * 8 + j][t] = s8[j];
    }
    __syncthreads();
    #pragma unroll
    for (int p = 0; p < 2; ++p) {
        int idx = tid + 256 * p;
        int d = idx >> 3, cc = idx & 7;
        short8 vv = *(const short8*)(&sh[d][cc * 8]);
        *(short8*)(vtb + ((size_t)bh * HD + d) * T_SEQ + tt * 64 + cc * 8) = vv;
    }
}

// ---------------------------------------------------------------------------
// Fused QKV GEMM: C[4096 x 3072] = xb[4096 x 1024] * wt^T, wt = [3072][1024].
// n = which*1024 + h*64 + d. Tile 128x128, BK=64, 4 waves (2x2, 64x64 each).
// Q (which==0) pre-scaled by 0.125*log2(e). Outputs bf16 [bh][t][d].
// grid (32, 24).
// ---------------------------------------------------------------------------
__global__ __launch_bounds__(256) void qkv_gemm(
    const short* __restrict__ xb, const short* __restrict__ wt,
    short* __restrict__ qb, short* __restrict__ kb, short* __restrict__ vb) {
    const int mt = blockIdx.x, ntg = blockIdx.y;
    const int m0 = mt * 128, n0 = ntg * 128;
    const int which = ntg >> 3;                         // uniform per block
    short* outp = (which == 0) ? qb : (which == 1) ? kb : vb;
    const float sc = (which == 0) ? 0.125f * 1.4426950408889634f : 1.0f;

    __shared__ short smem[2 * 128 * 72];                // 36.9 KB
    short (*As)[72] = (short(*)[72])smem;
    short (*Bs)[72] = (short(*)[72])(smem + 128 * 72);

    const int tid = threadIdx.x;
    const int lane = tid & 63, w = tid >> 6;
    const int wm = w & 1, wn = w >> 1;
    const int hi = lane >> 4, llo = lane & 15;

    floatx4 acc[4][4];
    #pragma unroll
    for (int i = 0; i < 4; ++i)
        #pragma unroll
        for (int j = 0; j < 4; ++j)
            #pragma unroll
            for (int r = 0; r < 4; ++r) acc[i][j][r] = 0.0f;

    for (int kt = 0; kt < C_DIM / 64; ++kt) {
        const int c0 = kt * 64;
        #pragma unroll
        for (int p = 0; p < 4; ++p) {                   // A: 128 x 8 chunks
            int idx = tid + 256 * p;
            int r = idx >> 3, cc = idx & 7;
            *(short8*)(&As[r][cc * 8]) =
                *(const short8*)(xb + (size_t)(m0 + r) * C_DIM + c0 + cc * 8);
        }
        #pragma unroll
        for (int p = 0; p < 4; ++p) {                   // B: 128 x 8 chunks
            int idx = tid + 256 * p;
            int r = idx >> 3, cc = idx & 7;
            *(short8*)(&Bs[r][cc * 8]) =
                *(const short8*)(wt + (size_t)(n0 + r) * C_DIM + c0 + cc * 8);
        }
        __syncthreads();

        short8 af[4][2];
        #pragma unroll
        for (int mi = 0; mi < 4; ++mi)
            #pragma unroll
            for (int kh = 0; kh < 2; ++kh)
                af[mi][kh] = *(const short8*)(&As[wm * 64 + mi * 16 + llo][kh * 32 + hi * 8]);
        #pragma unroll
        for (int ni = 0; ni < 4; ++ni) {
            short8 b0 = *(const short8*)(&Bs[wn * 64 + ni * 16 + llo][hi * 8]);
            short8 b1 = *(const short8*)(&Bs[wn * 64 + ni * 16 + llo][32 + hi * 8]);
            #pragma unroll
            for (int mi = 0; mi < 4; ++mi) {
                acc[mi][ni] = __builtin_amdgcn_mfma_f32_16x16x32_bf16(af[mi][0], b0, acc[mi][ni], 0, 0, 0);
                acc[mi][ni] = __builtin_amdgcn_mfma_f32_16x16x32_bf16(af[mi][1], b1, acc[mi][ni], 0, 0, 0);
            }
        }
        __syncthreads();
    }

    // epilogue: repack 128x128 bf16 via LDS, then vector copy-out
    short (*R)[136] = (short(*)[136])smem;              // 34.8 KB <= 36.9
    #pragma unroll
    for (int mi = 0; mi < 4; ++mi)
        #pragma unroll
        for (int ni = 0; ni < 4; ++ni)
            #pragma unroll
            for (int r = 0; r < 4; ++r)
                R[wm * 64 + mi * 16 + hi * 4 + r][wn * 64 + ni * 16 + llo] =
                    f2bf(acc[mi][ni][r] * sc);
    __syncthreads();
    #pragma unroll
    for (int p = 0; p < 8; ++p) {
        int idx = tid + 256 * p;                        // 2048 chunks: r(128) x cc(16)
        int r = idx >> 4, cc = idx & 15;
        short8 vv = *(const short8*)(&R[r][cc * 8]);
        int mg = m0 + r;
        int b = mg >> 11, t = mg & 2047;
        int n = n0 + cc * 8;
        int h = (n >> 6) & 15, d = n & 63;
        *(short8*)(outp + ((size_t)(b * H_NUM + h) * T_SEQ + t) * HD + d) = vv;
    }
}

// ---------------------------------------------------------------------------
// Flash attention, bf16 MFMA, exp2-domain online softmax.
// grid (x=bh 32, y=32), qt = 31-y  (heavy blocks dispatch first; x-major
// order keeps all q-tiles of one bh on the same XCD for K/V L2 reuse).
// ---------------------------------------------------------------------------
__global__ __launch_bounds__(256) void attn_mfma(
    const short* __restrict__ qb, const short* __restrict__ kb,
    const short* __restrict__ vtb, short* __restrict__ attb) {
    const int bh = blockIdx.x;
    const int qt = 31 - blockIdx.y;
    const int b = bh >> 4, h = bh & 15;
    const short* K  = kb  + (size_t)bh * T_SEQ * HD;    // [s][d]
    const short* Vt = vtb + (size_t)bh * HD * T_SEQ;    // [d][s]
    const short* Q  = qb + ((size_t)bh * T_SEQ + qt * 64) * HD;

    __shared__ short Qs[64][72];
    __shared__ short Ks[64][72];
    __shared__ short Vts[64][72];
    __shared__ short Ps[64][72];

    const int tid = threadIdx.x;
    const int lane = tid & 63, w = tid >> 6;
    const int hi = lane >> 4, llo = lane & 15;

    // stage Q tile (first k-iter barrier covers it)
    #pragma unroll
    for (int p = 0; p < 2; ++p) {
        int idx = tid + 256 * p;
        int r = idx >> 3, cc = idx & 7;
        *(short8*)(&Qs[r][cc * 8]) = *(const short8*)(Q + (size_t)r * HD + cc * 8);
    }

    float mrow[4], lrow[4];
    floatx4 Oa[4];
    #pragma unroll
    for (int r = 0; r < 4; ++r) { mrow[r] = -3.0e38f; lrow[r] = 0.0f; }
    #pragma unroll
    for (int nt = 0; nt < 4; ++nt)
        #pragma unroll
        for (int r = 0; r < 4; ++r) Oa[nt][r] = 0.0f;

    for (int kt = 0; kt <= qt; ++kt) {
        #pragma unroll
        for (int p = 0; p < 2; ++p) {
            int idx = tid + 256 * p;
            int r = idx >> 3, cc = idx & 7;
            *(short8*)(&Ks[r][cc * 8]) =
                *(const short8*)(K + ((size_t)kt * 64 + r) * HD + cc * 8);
        }
        #pragma unroll
        for (int p = 0; p < 2; ++p) {
            int idx = tid + 256 * p;
            int r = idx >> 3, cc = idx & 7;
            *(short8*)(&Vts[r][cc * 8]) =
                *(const short8*)(Vt + (size_t)r * T_SEQ + kt * 64 + cc * 8);
        }
        __syncthreads();

        // S = Q K^T  (wave w owns rows w*16..w*16+15)
        short8 aq[2];
        #pragma unroll
        for (int kh = 0; kh < 2; ++kh)
            aq[kh] = *(const short8*)(&Qs[w * 16 + llo][kh * 32 + hi * 8]);
        floatx4 sf[4];
        #pragma unroll
        for (int nt = 0; nt < 4; ++nt)
            #pragma unroll
            for (int r = 0; r < 4; ++r) sf[nt][r] = 0.0f;
        #pragma unroll
        for (int nt = 0; nt < 4; ++nt)
            #pragma unroll
            for (int kh = 0; kh < 2; ++kh) {
                short8 bk = *(const short8*)(&Ks[nt * 16 + llo][kh * 32 + hi * 8]);
                sf[nt] = __builtin_amdgcn_mfma_f32_16x16x32_bf16(aq[kh], bk, sf[nt], 0, 0, 0);
            }

        if (kt == qt) {                                 // causal mask (diag tile)
            const int rbase = w * 16 + hi * 4;
            #pragma unroll
            for (int nt = 0; nt < 4; ++nt)
                #pragma unroll
                for (int r = 0; r < 4; ++r)
                    if (nt * 16 + llo > rbase + r) sf[nt][r] = -3.0e38f;
        }

        // online softmax (exp2 domain; scale folded into Q)
        float alpha[4], rs[4];
        #pragma unroll
        for (int r = 0; r < 4; ++r) {
            float rm = fmaxf(fmaxf(sf[0][r], sf[1][r]), fmaxf(sf[2][r], sf[3][r]));
            #pragma unroll
            for (int off = 1; off < 16; off <<= 1)
                rm = fmaxf(rm, __shfl_xor(rm, off));
            float mn = fmaxf(mrow[r], rm);
            alpha[r] = __builtin_amdgcn_exp2f(mrow[r] - mn);
            mrow[r] = mn;
            rs[r] = 0.0f;
        }
        #pragma unroll
        for (int nt = 0; nt < 4; ++nt)
            #pragma unroll
            for (int r = 0; r < 4; ++r) {
                float pp = __builtin_amdgcn_exp2f(sf[nt][r] - mrow[r]);
                sf[nt][r] = pp;
                rs[r] += pp;
            }
        #pragma unroll
        for (int r = 0; r < 4; ++r) {
            #pragma unroll
            for (int off = 1; off < 16; off <<= 1)
                rs[r] += __shfl_xor(rs[r], off);
            lrow[r] = lrow[r] * alpha[r] + rs[r];
        }
        #pragma unroll
        for (int nt = 0; nt < 4; ++nt)
            #pragma unroll
            for (int r = 0; r < 4; ++r) Oa[nt][r] *= alpha[r];

        // P (C-layout) -> LDS bf16 (A-layout source); same-wave rows only
        #pragma unroll
        for (int nt = 0; nt < 4; ++nt)
            #pragma unroll
            for (int r = 0; r < 4; ++r)
                Ps[w * 16 + hi * 4 + r][nt * 16 + llo] = f2bf(sf[nt][r]);

        // O += P V
        short8 ap[2];
        #pragma unroll
        for (int kh = 0; kh < 2; ++kh)
            ap[kh] = *(const short8*)(&Ps[w * 16 + llo][kh * 32 + hi * 8]);
        #pragma unroll
        for (int nt = 0; nt < 4; ++nt)
            #pragma unroll
            for (int kh = 0; kh < 2; ++kh) {
                short8 bv = *(const short8*)(&Vts[nt * 16 + llo][kh * 32 + hi * 8]);
                Oa[nt] = __builtin_amdgcn_mfma_f32_16x16x32_bf16(ap[kh], bv, Oa[nt], 0, 0, 0);
            }
        __syncthreads();
    }

    // epilogue: O/l -> bf16 via Ps, vector copy to att[b][t][h*64+d]
    #pragma unroll
    for (int nt = 0; nt < 4; ++nt)
        #pragma unroll
        for (int r = 0; r < 4; ++r)
            Ps[w * 16 + hi * 4 + r][nt * 16 + llo] = f2bf(Oa[nt][r] / lrow[r]);
    __syncthreads();
    #pragma unroll
    for (int p = 0; p < 2; ++p) {
        int idx = tid + 256 * p;
        int r = idx >> 3, cc = idx & 7;
        short8 vv = *(const short8*)(&Ps[r][cc * 8]);
        *(short8*)(attb + ((size_t)(b * T_SEQ + qt * 64 + r)) * C_DIM + h * HD + cc * 8) = vv;
    }
}

// ---------------------------------------------------------------------------
// Output projection: out = att(bf16) @ Wp + bp, fp32 out.
// grid (32, 16), block 256. Tile 128 x 64, BK=64. B from Wpt [n][k].
// ---------------------------------------------------------------------------
__global__ __launch_bounds__(256) void proj_gemm(
    const short* __restrict__ attb, const short* __restrict__ wpt,
    const float* __restrict__ bp, float* __restrict__ out) {
    const int mt = blockIdx.x, nt_g = blockIdx.y;
    const int m0 = mt * 128, n0 = nt_g * 64;

    __shared__ short As[128][72];
    __shared__ short Bst[64][72];

    const int tid = threadIdx.x;
    const int lane = tid & 63, w = tid >> 6;
    const int hi = lane >> 4, llo = lane & 15;

    floatx4 acc[2][4];
    #pragma unroll
    for (int i = 0; i < 2; ++i)
        #pragma unroll
        for (int j = 0; j < 4; ++j)
            #pragma unroll
            for (int r = 0; r < 4; ++r) acc[i][j][r] = 0.0f;

    for (int kt = 0; kt < C_DIM / 64; ++kt) {
        const int c0 = kt * 64;
        #pragma unroll
        for (int p = 0; p < 4; ++p) {
            int idx = tid + 256 * p;
            int r = idx >> 3, cc = idx & 7;
            *(short8*)(&As[r][cc * 8]) =
                *(const short8*)(attb + (size_t)(m0 + r) * C_DIM + c0 + cc * 8);
        }
        #pragma unroll
        for (int p = 0; p < 2; ++p) {
            int idx = tid + 256 * p;
            int n = idx >> 3, cc = idx & 7;
            *(short8*)(&Bst[n][cc * 8]) =
                *(const short8*)(wpt + (size_t)(n0 + n) * C_DIM + c0 + cc * 8);
        }
        __syncthreads();

        short8 af[2][2];
        #pragma unroll
        for (int m2 = 0; m2 < 2; ++m2)
            #pragma unroll
            for (int kh = 0; kh < 2; ++kh)
                af[m2][kh] = *(const short8*)(&As[w * 32 + m2 * 16 + llo][kh * 32 + hi * 8]);
        #pragma unroll
        for (int nt = 0; nt < 4; ++nt)
            #pragma unroll
            for (int kh = 0; kh < 2; ++kh) {
                short8 bf = *(const short8*)(&Bst[nt * 16 + llo][kh * 32 + hi * 8]);
                #pragma unroll
                for (int m2 = 0; m2 < 2; ++m2)
                    acc[m2][nt] = __builtin_amdgcn_mfma_f32_16x16x32_bf16(
                        af[m2][kh], bf, acc[m2][nt], 0, 0, 0);
            }
        __syncthreads();
    }

    #pragma unroll
    for (int nt = 0; nt < 4; ++nt) {
        const int n = n0 + nt * 16 + llo;
        const float bias = bp[n];
        #pragma unroll
        for (int m2 = 0; m2 < 2; ++m2)
            #pragma unroll
            for (int r = 0; r < 4; ++r) {
                int m = m0 + w * 32 + m2 * 16 + hi * 4 + r;
                out[(size_t)m * C_DIM + n] = acc[m2][nt][r] + bias;
            }
    }
}

// ---------------------------------------------------------------------------
extern "C" void kernel_launch(void* const* d_in, const int* in_sizes, int n_in,
                              void* d_out, int out_size, void* d_ws, size_t ws_size,
                              hipStream_t stream) {
    const float* x  = (const float*)d_in[0];
    const float* Wq = (const float*)d_in[1];
    const float* Wk = (const float*)d_in[2];
    const float* Wv = (const float*)d_in[3];
    const float* Wp = (const float*)d_in[4];
    const float* bp = (const float*)d_in[5];
    float* out = (float*)d_out;

    short* xb   = (short*)d_ws;                          // 4M shorts
    short* wt   = xb  + (size_t)M_TOT * C_DIM;           // 3M
    short* wpt  = wt  + (size_t)3 * H_NUM * HD * C_DIM;  // 1M
    short* qb   = wpt + (size_t)C_DIM * C_DIM;           // 4M each
    short* kb   = qb  + (size_t)M_TOT * C_DIM;
    short* vb   = kb  + (size_t)M_TOT * C_DIM;
    short* vtb  = vb  + (size_t)M_TOT * C_DIM;
    short* attb = vtb + (size_t)M_TOT * C_DIM;

    convert_x  <<<dim3(M_TOT * C_DIM / 2048), 256, 0, stream>>>(x, xb);
    transp_wqkv<<<dim3(16, 48), 256, 0, stream>>>(Wq, Wk, Wv, wt);
    transp_wp  <<<dim3(16, 16), 256, 0, stream>>>(Wp, wpt);
    qkv_gemm   <<<dim3(M_TOT / 128, 3 * C_DIM / 128), 256, 0, stream>>>(xb, wt, qb, kb, vb);
    transp_v   <<<dim3(T_SEQ / 64, BH_N), 256, 0, stream>>>(vb, vtb);
    attn_mfma  <<<dim3(BH_N, T_SEQ / 64), 256, 0, stream>>>(qb, kb, vtb, attb);
    proj_gemm  <<<dim3(M_TOT / 128, C_DIM / 64), 256, 0, stream>>>(attb, wpt, bp, out);
}

// Round 5
// 184.982 us; speedup vs baseline: 6.2577x; 1.1895x over previous
//
#include <hip/hip_runtime.h>
#include <hip/hip_bf16.h>

#define B_NUM 2
#define T_SEQ 2048
#define C_DIM 1024
#define H_NUM 16
#define HD    64
#define M_TOT 4096
#define BH_N  32

typedef __attribute__((ext_vector_type(8))) short short8;   // 8 bf16
typedef __attribute__((ext_vector_type(4))) float floatx4;  // 4 fp32 acc

__device__ __forceinline__ short f2bf(float f) {
    unsigned u = __float_as_uint(f);
    u += 0x7FFFu + ((u >> 16) & 1u);
    return (short)(u >> 16);
}

// packed fp32x2 -> bf16x2 (RNE); emits v_cvt_pk_bf16_f32 on gfx950
__device__ __forceinline__ unsigned pk2bf(float a, float b) {
    float2 f2; f2.x = a; f2.y = b;
    __hip_bfloat162 h = __float22bfloat162_rn(f2);
    unsigned u; __builtin_memcpy(&u, &h, 4); return u;
}

// ---------------------------------------------------------------------------
// x fp32 -> bf16, elementwise.
// ---------------------------------------------------------------------------
__global__ __launch_bounds__(256) void convert_x(const float* __restrict__ x,
                                                 short* __restrict__ xb) {
    int idx = (blockIdx.x * 256 + threadIdx.x) * 8;
    float4 a = *(const float4*)(x + idx);
    float4 b = *(const float4*)(x + idx + 4);
    short8 o;
    o[0] = f2bf(a.x); o[1] = f2bf(a.y); o[2] = f2bf(a.z); o[3] = f2bf(a.w);
    o[4] = f2bf(b.x); o[5] = f2bf(b.y); o[6] = f2bf(b.z); o[7] = f2bf(b.w);
    *(short8*)(xb + idx) = o;
}

// ---------------------------------------------------------------------------
// Fused weight transpose+convert.
// y<48: Wq/Wk/Wv [h][c][d] -> wt [which*16+h][d][c]  (flat [3072][1024])
// y>=48: Wp [k][n] -> wpt [n][k]
// grid (16, 64).
// ---------------------------------------------------------------------------
__global__ __launch_bounds__(256) void transp_w(
    const float* __restrict__ Wq, const float* __restrict__ Wk,
    const float* __restrict__ Wv, const float* __restrict__ Wp,
    short* __restrict__ wt, short* __restrict__ wpt) {
    const int ct = blockIdx.x, y = blockIdx.y;
    __shared__ short sh[64][72];
    const int tid = threadIdx.x;
    if (y < 48) {
        const int which = y >> 4, h = y & 15;
        const float* W = ((which == 0) ? Wq : (which == 1) ? Wk : Wv) + (size_t)h * C_DIM * HD;
        const int c0 = ct * 64;
        #pragma unroll
        for (int p = 0; p < 4; ++p) {
            int idx = tid + 256 * p;
            int c = idx >> 4, d4 = idx & 15;
            float4 v = *(const float4*)(W + (size_t)(c0 + c) * HD + d4 * 4);
            sh[d4 * 4 + 0][c] = f2bf(v.x);
            sh[d4 * 4 + 1][c] = f2bf(v.y);
            sh[d4 * 4 + 2][c] = f2bf(v.z);
            sh[d4 * 4 + 3][c] = f2bf(v.w);
        }
        __syncthreads();
        #pragma unroll
        for (int p = 0; p < 2; ++p) {
            int idx = tid + 256 * p;
            int d = idx >> 3, cc = idx & 7;
            short8 vv = *(const short8*)(&sh[d][cc * 8]);
            *(short8*)(wt + ((size_t)(which * 16 + h) * 64 + d) * C_DIM + c0 + cc * 8) = vv;
        }
    } else {
        const int nt = y - 48;
        #pragma unroll
        for (int p = 0; p < 4; ++p) {
            int idx = tid + 256 * p;
            int k = idx >> 4, n4 = idx & 15;
            float4 v = *(const float4*)(Wp + (size_t)(ct * 64 + k) * C_DIM + nt * 64 + n4 * 4);
            sh[n4 * 4 + 0][k] = f2bf(v.x);
            sh[n4 * 4 + 1][k] = f2bf(v.y);
            sh[n4 * 4 + 2][k] = f2bf(v.z);
            sh[n4 * 4 + 3][k] = f2bf(v.w);
        }
        __syncthreads();
        #pragma unroll
        for (int p = 0; p < 2; ++p) {
            int idx = tid + 256 * p;
            int n = idx >> 3, cc = idx & 7;
            short8 vv = *(const short8*)(&sh[n][cc * 8]);
            *(short8*)(wpt + (size_t)(nt * 64 + n) * C_DIM + ct * 64 + cc * 8) = vv;
        }
    }
}

// ---------------------------------------------------------------------------
// Fused QKV GEMM: [4096 x 3072] = xb[4096 x 1024] * wt^T. Tile 128x128, BK=64.
// which = n0/1024: 0 -> qb [bh][t][d] (scaled), 1 -> kb [bh][t][d],
// 2 -> vtb [bh][d][t] (transposed epilogue). Register-prefetch pipeline.
// grid (32, 24).
// ---------------------------------------------------------------------------
__global__ __launch_bounds__(256) void qkv_gemm(
    const short* __restrict__ xb, const short* __restrict__ wt,
    short* __restrict__ qb, short* __restrict__ kb, short* __restrict__ vtb) {
    const int mt = blockIdx.x, ntg = blockIdx.y;
    const int m0 = mt * 128, n0 = ntg * 128;
    const int which = ntg >> 3;
    const float sc = (which == 0) ? 0.125f * 1.4426950408889634f : 1.0f;

    __shared__ short smem[2 * 128 * 72];                // 36.9 KB
    short (*As)[72] = (short(*)[72])smem;
    short (*Bs)[72] = (short(*)[72])(smem + 128 * 72);

    const int tid = threadIdx.x;
    const int lane = tid & 63, w = tid >> 6;
    const int wm = w & 1, wn = w >> 1;
    const int hi = lane >> 4, llo = lane & 15;

    floatx4 acc[4][4];
    #pragma unroll
    for (int i = 0; i < 4; ++i)
        #pragma unroll
        for (int j = 0; j < 4; ++j)
            #pragma unroll
            for (int r = 0; r < 4; ++r) acc[i][j][r] = 0.0f;

    const int r_ = tid >> 3, cc_ = tid & 7;
    short8 areg[4], breg[4];

    {   // preload tile 0
        #pragma unroll
        for (int p = 0; p < 4; ++p) {
            int rr = r_ + 32 * p;
            areg[p] = *(const short8*)(xb + (size_t)(m0 + rr) * C_DIM + cc_ * 8);
            breg[p] = *(const short8*)(wt + (size_t)(n0 + rr) * C_DIM + cc_ * 8);
        }
    }

    for (int kt = 0; kt < C_DIM / 64; ++kt) {
        #pragma unroll
        for (int p = 0; p < 4; ++p) {
            int rr = r_ + 32 * p;
            *(short8*)(&As[rr][cc_ * 8]) = areg[p];
            *(short8*)(&Bs[rr][cc_ * 8]) = breg[p];
        }
        __syncthreads();
        if (kt + 1 < C_DIM / 64) {
            const int c0 = (kt + 1) * 64;
            #pragma unroll
            for (int p = 0; p < 4; ++p) {
                int rr = r_ + 32 * p;
                areg[p] = *(const short8*)(xb + (size_t)(m0 + rr) * C_DIM + c0 + cc_ * 8);
                breg[p] = *(const short8*)(wt + (size_t)(n0 + rr) * C_DIM + c0 + cc_ * 8);
            }
        }

        short8 af[4][2];
        #pragma unroll
        for (int mi = 0; mi < 4; ++mi)
            #pragma unroll
            for (int kh = 0; kh < 2; ++kh)
                af[mi][kh] = *(const short8*)(&As[wm * 64 + mi * 16 + llo][kh * 32 + hi * 8]);
        #pragma unroll
        for (int ni = 0; ni < 4; ++ni) {
            short8 b0 = *(const short8*)(&Bs[wn * 64 + ni * 16 + llo][hi * 8]);
            short8 b1 = *(const short8*)(&Bs[wn * 64 + ni * 16 + llo][32 + hi * 8]);
            #pragma unroll
            for (int mi = 0; mi < 4; ++mi) {
                acc[mi][ni] = __builtin_amdgcn_mfma_f32_16x16x32_bf16(af[mi][0], b0, acc[mi][ni], 0, 0, 0);
                acc[mi][ni] = __builtin_amdgcn_mfma_f32_16x16x32_bf16(af[mi][1], b1, acc[mi][ni], 0, 0, 0);
            }
        }
        __syncthreads();
    }

    short (*R)[136] = (short(*)[136])smem;              // 34.8 KB <= 36.9
    if (which == 2) {
        // store transposed: R[n][m] so copy-out is coalesced over t
        #pragma unroll
        for (int mi = 0; mi < 4; ++mi)
            #pragma unroll
            for (int ni = 0; ni < 4; ++ni)
                #pragma unroll
                for (int r = 0; r < 4; ++r)
                    R[wn * 64 + ni * 16 + llo][wm * 64 + mi * 16 + hi * 4 + r] =
                        f2bf(acc[mi][ni][r]);
        __syncthreads();
        const int b = m0 >> 11;
        #pragma unroll
        for (int p = 0; p < 8; ++p) {
            int idx = tid + 256 * p;                    // 2048 chunks: n(128) x m-chunk(16)
            int rr = idx >> 4, cc = idx & 15;
            short8 vv = *(const short8*)(&R[rr][cc * 8]);
            int n = n0 + rr;
            int h = (n >> 6) & 15, d = n & 63;
            int t = (m0 & 2047) + cc * 8;
            *(short8*)(vtb + ((size_t)((b * H_NUM + h) * HD + d)) * T_SEQ + t) = vv;
        }
    } else {
        short* outp = (which == 0) ? qb : kb;
        #pragma unroll
        for (int mi = 0; mi < 4; ++mi)
            #pragma unroll
            for (int ni = 0; ni < 4; ++ni)
                #pragma unroll
                for (int r = 0; r < 4; ++r)
                    R[wm * 64 + mi * 16 + hi * 4 + r][wn * 64 + ni * 16 + llo] =
                        f2bf(acc[mi][ni][r] * sc);
        __syncthreads();
        #pragma unroll
        for (int p = 0; p < 8; ++p) {
            int idx = tid + 256 * p;                    // 2048 chunks: m(128) x n-chunk(16)
            int r = idx >> 4, cc = idx & 15;
            short8 vv = *(const short8*)(&R[r][cc * 8]);
            int mg = m0 + r;
            int b = mg >> 11, t = mg & 2047;
            int n = n0 + cc * 8;
            int h = (n >> 6) & 15, d = n & 63;
            *(short8*)(outp + ((size_t)(b * H_NUM + h) * T_SEQ + t) * HD + d) = vv;
        }
    }
}

// ---------------------------------------------------------------------------
// Flash attention, transposed dataflow: S^T = K Q^T, O^T = V^T_ext P^T.
// Ones-row in V^T computes l via MFMA. Stats per-lane (q = lane&15).
// q-tile 128 (wave = 32 q-rows), k-tile 64, dbuf LDS + reg prefetch,
// 1 barrier/iter. Q-frags in registers. grid (bh=32, 16).
// ---------------------------------------------------------------------------
__global__ __launch_bounds__(256) void attn_mfma(
    const short* __restrict__ qb, const short* __restrict__ kb,
    const short* __restrict__ vtb, short* __restrict__ attb) {
    const int bh = blockIdx.x;
    const int y = blockIdx.y;
    const int qt = (y < 8) ? (15 - y) : (y - 8);      // balanced pairing per CU
    const int b = bh >> 4, h = bh & 15;
    const short* K  = kb  + (size_t)bh * T_SEQ * HD;   // [s][d]
    const short* Vt = vtb + (size_t)bh * HD * T_SEQ;   // [d][s]

    __shared__ short Ks[2][64][72];    // 18.4 KB
    __shared__ short Vts[2][80][72];   // 23.0 KB (rows 64..79: ones/zeros)
    __shared__ short Ps[128][72];      // 18.4 KB  (P^T rows=q, also O epilogue)

    const int tid = threadIdx.x;
    const int lane = tid & 63, w = tid >> 6;
    const int hi = lane >> 4, llo = lane & 15;
    const int kmax = 2 * qt + 1;

    // Q B-frags straight from global (no LDS)
    short8 qf[2][2];
    const int qrow0 = qt * 128 + w * 32;
    #pragma unroll
    for (int g = 0; g < 2; ++g)
        #pragma unroll
        for (int kh = 0; kh < 2; ++kh)
            qf[g][kh] = *(const short8*)(qb +
                ((size_t)bh * T_SEQ + qrow0 + g * 16 + llo) * HD + kh * 32 + hi * 8);

    // ones rows (d=64) / zero rows (65..79), both buffers
    for (int i = tid; i < 16 * 72; i += 256) {
        int r = 64 + i / 72, c = i % 72;
        short v = (r == 64 && c < 64) ? (short)0x3F80 : (short)0;
        Vts[0][r][c] = v;
        Vts[1][r][c] = v;
    }

    const int r_ = tid >> 3, cc_ = tid & 7;            // staging coords (r<32 per pass)
    short8 kreg[2], vreg[2];
    // preload tile 0
    #pragma unroll
    for (int p = 0; p < 2; ++p) {
        int rr = r_ + 32 * p;
        kreg[p] = *(const short8*)(K + (size_t)rr * HD + cc_ * 8);
        vreg[p] = *(const short8*)(Vt + (size_t)rr * T_SEQ + cc_ * 8);
    }
    #pragma unroll
    for (int p = 0; p < 2; ++p) {
        int rr = r_ + 32 * p;
        *(short8*)(&Ks[0][rr][cc_ * 8]) = kreg[p];
        *(short8*)(&Vts[0][rr][cc_ * 8]) = vreg[p];
    }
    if (kmax >= 1) {
        #pragma unroll
        for (int p = 0; p < 2; ++p) {
            int rr = r_ + 32 * p;
            kreg[p] = *(const short8*)(K + ((size_t)64 + rr) * HD + cc_ * 8);
            vreg[p] = *(const short8*)(Vt + (size_t)rr * T_SEQ + 64 + cc_ * 8);
        }
    }

    float m_i[2] = {-3.0e38f, -3.0e38f};
    floatx4 Oa[2][5];
    #pragma unroll
    for (int g = 0; g < 2; ++g)
        #pragma unroll
        for (int n = 0; n < 5; ++n)
            #pragma unroll
            for (int r = 0; r < 4; ++r) Oa[g][n][r] = 0.0f;

    for (int kt = 0; kt <= kmax; ++kt) {
        __syncthreads();                               // buf[kt&1] fully staged
        const int buf = kt & 1;

        // S^T = K Q^T
        short8 ak[4][2];
        #pragma unroll
        for (int nt = 0; nt < 4; ++nt)
            #pragma unroll
            for (int kh = 0; kh < 2; ++kh)
                ak[nt][kh] = *(const short8*)(&Ks[buf][nt * 16 + llo][kh * 32 + hi * 8]);
        floatx4 sf[2][4];
        #pragma unroll
        for (int g = 0; g < 2; ++g)
            #pragma unroll
            for (int nt = 0; nt < 4; ++nt)
                #pragma unroll
                for (int r = 0; r < 4; ++r) sf[g][nt][r] = 0.0f;
        #pragma unroll
        for (int nt = 0; nt < 4; ++nt)
            #pragma unroll
            for (int kh = 0; kh < 2; ++kh)
                #pragma unroll
                for (int g = 0; g < 2; ++g)
                    sf[g][nt] = __builtin_amdgcn_mfma_f32_16x16x32_bf16(
                        ak[nt][kh], qf[g][kh], sf[g][nt], 0, 0, 0);

        // causal mask (only near diagonal)
        const int sbase = kt * 64;
        #pragma unroll
        for (int g = 0; g < 2; ++g) {
            const int qg = qt * 128 + w * 32 + g * 16;
            if (sbase + 63 > qg) {
                const int qlane = qg + llo;
                #pragma unroll
                for (int nt = 0; nt < 4; ++nt)
                    #pragma unroll
                    for (int r = 0; r < 4; ++r)
                        if (sbase + nt * 16 + hi * 4 + r > qlane) sf[g][nt][r] = -3.0e38f;
            }
        }

        // per-lane online softmax (q = lane&15 within g-block)
        #pragma unroll
        for (int g = 0; g < 2; ++g) {
            float rm = sf[g][0][0];
            #pragma unroll
            for (int nt = 0; nt < 4; ++nt)
                #pragma unroll
                for (int r = 0; r < 4; ++r) rm = fmaxf(rm, sf[g][nt][r]);
            rm = fmaxf(rm, __shfl_xor(rm, 16));
            rm = fmaxf(rm, __shfl_xor(rm, 32));
            float mn = fmaxf(m_i[g], rm);
            float alpha = __builtin_amdgcn_exp2f(m_i[g] - mn);
            m_i[g] = mn;
            // P^T -> bf16 packed -> Ps (same-wave rows; no barrier)
            #pragma unroll
            for (int nt = 0; nt < 4; ++nt) {
                float p0 = __builtin_amdgcn_exp2f(sf[g][nt][0] - mn);
                float p1 = __builtin_amdgcn_exp2f(sf[g][nt][1] - mn);
                float p2 = __builtin_amdgcn_exp2f(sf[g][nt][2] - mn);
                float p3 = __builtin_amdgcn_exp2f(sf[g][nt][3] - mn);
                uint2 u; u.x = pk2bf(p0, p1); u.y = pk2bf(p2, p3);
                *(uint2*)(&Ps[w * 32 + g * 16 + llo][nt * 16 + hi * 4]) = u;
            }
            #pragma unroll
            for (int n = 0; n < 5; ++n)
                #pragma unroll
                for (int r = 0; r < 4; ++r) Oa[g][n][r] *= alpha;
        }

        // O^T += V^T_ext P^T   (nt2==4 row accumulates l)
        short8 av[5][2];
        #pragma unroll
        for (int nt2 = 0; nt2 < 5; ++nt2)
            #pragma unroll
            for (int kh = 0; kh < 2; ++kh)
                av[nt2][kh] = *(const short8*)(&Vts[buf][nt2 * 16 + llo][kh * 32 + hi * 8]);
        short8 bp[2][2];
        #pragma unroll
        for (int g = 0; g < 2; ++g)
            #pragma unroll
            for (int kh = 0; kh < 2; ++kh)
                bp[g][kh] = *(const short8*)(&Ps[w * 32 + g * 16 + llo][kh * 32 + hi * 8]);
        #pragma unroll
        for (int nt2 = 0; nt2 < 5; ++nt2)
            #pragma unroll
            for (int kh = 0; kh < 2; ++kh)
                #pragma unroll
                for (int g = 0; g < 2; ++g)
                    Oa[g][nt2] = __builtin_amdgcn_mfma_f32_16x16x32_bf16(
                        av[nt2][kh], bp[g][kh], Oa[g][nt2], 0, 0, 0);

        // stage tile kt+1 into other buffer, then start loads for kt+2
        if (kt + 1 <= kmax) {
            const int nbuf = (kt + 1) & 1;
            #pragma unroll
            for (int p = 0; p < 2; ++p) {
                int rr = r_ + 32 * p;
                *(short8*)(&Ks[nbuf][rr][cc_ * 8]) = kreg[p];
                *(short8*)(&Vts[nbuf][rr][cc_ * 8]) = vreg[p];
            }
        }
        if (kt + 2 <= kmax) {
            const int s0 = (kt + 2) * 64;
            #pragma unroll
            for (int p = 0; p < 2; ++p) {
                int rr = r_ + 32 * p;
                kreg[p] = *(const short8*)(K + ((size_t)s0 + rr) * HD + cc_ * 8);
                vreg[p] = *(const short8*)(Vt + (size_t)rr * T_SEQ + s0 + cc_ * 8);
            }
        }
    }

    // epilogue: O = O^T/l, bf16, into Ps (same-wave rows), then coalesced out
    #pragma unroll
    for (int g = 0; g < 2; ++g) {
        float lb = __shfl(Oa[g][4][0], llo);           // l lives in lanes hi==0
        float inv = 1.0f / lb;
        #pragma unroll
        for (int nt2 = 0; nt2 < 4; ++nt2) {
            uint2 u;
            u.x = pk2bf(Oa[g][nt2][0] * inv, Oa[g][nt2][1] * inv);
            u.y = pk2bf(Oa[g][nt2][2] * inv, Oa[g][nt2][3] * inv);
            *(uint2*)(&Ps[w * 32 + g * 16 + llo][nt2 * 16 + hi * 4]) = u;
        }
    }
    __syncthreads();
    #pragma unroll
    for (int p = 0; p < 4; ++p) {
        int idx = tid + 256 * p;                       // 1024 chunks: q(128) x d-chunk(8)
        int r = idx >> 3, cc = idx & 7;
        short8 vv = *(const short8*)(&Ps[r][cc * 8]);
        *(short8*)(attb + ((size_t)(b * T_SEQ + qt * 128 + r)) * C_DIM + h * HD + cc * 8) = vv;
    }
}

// ---------------------------------------------------------------------------
// Output projection: out = att(bf16) @ Wp + bp, fp32 out.
// grid (32, 16), block 256. Tile 128 x 64, BK=64, reg-prefetch.
// ---------------------------------------------------------------------------
__global__ __launch_bounds__(256) void proj_gemm(
    const short* __restrict__ attb, const short* __restrict__ wpt,
    const float* __restrict__ bp, float* __restrict__ out) {
    const int mt = blockIdx.x, nt_g = blockIdx.y;
    const int m0 = mt * 128, n0 = nt_g * 64;

    __shared__ short As[128][72];
    __shared__ short Bst[64][72];

    const int tid = threadIdx.x;
    const int lane = tid & 63, w = tid >> 6;
    const int hi = lane >> 4, llo = lane & 15;
    const int r_ = tid >> 3, cc_ = tid & 7;

    floatx4 acc[2][4];
    #pragma unroll
    for (int i = 0; i < 2; ++i)
        #pragma unroll
        for (int j = 0; j < 4; ++j)
            #pragma unroll
            for (int r = 0; r < 4; ++r) acc[i][j][r] = 0.0f;

    short8 areg[4], breg[2];
    #pragma unroll
    for (int p = 0; p < 4; ++p)
        areg[p] = *(const short8*)(attb + (size_t)(m0 + r_ + 32 * p) * C_DIM + cc_ * 8);
    #pragma unroll
    for (int p = 0; p < 2; ++p)
        breg[p] = *(const short8*)(wpt + (size_t)(n0 + r_ + 32 * p) * C_DIM + cc_ * 8);

    for (int kt = 0; kt < C_DIM / 64; ++kt) {
        #pragma unroll
        for (int p = 0; p < 4; ++p)
            *(short8*)(&As[r_ + 32 * p][cc_ * 8]) = areg[p];
        #pragma unroll
        for (int p = 0; p < 2; ++p)
            *(short8*)(&Bst[r_ + 32 * p][cc_ * 8]) = breg[p];
        __syncthreads();
        if (kt + 1 < C_DIM / 64) {
            const int c0 = (kt + 1) * 64;
            #pragma unroll
            for (int p = 0; p < 4; ++p)
                areg[p] = *(const short8*)(attb + (size_t)(m0 + r_ + 32 * p) * C_DIM + c0 + cc_ * 8);
            #pragma unroll
            for (int p = 0; p < 2; ++p)
                breg[p] = *(const short8*)(wpt + (size_t)(n0 + r_ + 32 * p) * C_DIM + c0 + cc_ * 8);
        }

        short8 af[2][2];
        #pragma unroll
        for (int m2 = 0; m2 < 2; ++m2)
            #pragma unroll
            for (int kh = 0; kh < 2; ++kh)
                af[m2][kh] = *(const short8*)(&As[w * 32 + m2 * 16 + llo][kh * 32 + hi * 8]);
        #pragma unroll
        for (int nt = 0; nt < 4; ++nt)
            #pragma unroll
            for (int kh = 0; kh < 2; ++kh) {
                short8 bf = *(const short8*)(&Bst[nt * 16 + llo][kh * 32 + hi * 8]);
                #pragma unroll
                for (int m2 = 0; m2 < 2; ++m2)
                    acc[m2][nt] = __builtin_amdgcn_mfma_f32_16x16x32_bf16(
                        af[m2][kh], bf, acc[m2][nt], 0, 0, 0);
            }
        __syncthreads();
    }

    #pragma unroll
    for (int nt = 0; nt < 4; ++nt) {
        const int n = n0 + nt * 16 + llo;
        const float bias = bp[n];
        #pragma unroll
        for (int m2 = 0; m2 < 2; ++m2)
            #pragma unroll
            for (int r = 0; r < 4; ++r) {
                int m = m0 + w * 32 + m2 * 16 + hi * 4 + r;
                out[(size_t)m * C_DIM + n] = acc[m2][nt][r] + bias;
            }
    }
}

// ---------------------------------------------------------------------------
extern "C" void kernel_launch(void* const* d_in, const int* in_sizes, int n_in,
                              void* d_out, int out_size, void* d_ws, size_t ws_size,
                              hipStream_t stream) {
    const float* x  = (const float*)d_in[0];
    const float* Wq = (const float*)d_in[1];
    const float* Wk = (const float*)d_in[2];
    const float* Wv = (const float*)d_in[3];
    const float* Wp = (const float*)d_in[4];
    const float* bp = (const float*)d_in[5];
    float* out = (float*)d_out;

    short* xb   = (short*)d_ws;                          // 4M shorts
    short* wt   = xb  + (size_t)M_TOT * C_DIM;           // 3M
    short* wpt  = wt  + (size_t)3 * H_NUM * HD * C_DIM;  // 1M
    short* qb   = wpt + (size_t)C_DIM * C_DIM;           // 4M each
    short* kb   = qb  + (size_t)M_TOT * C_DIM;
    short* vtb  = kb  + (size_t)M_TOT * C_DIM;
    short* attb = vtb + (size_t)M_TOT * C_DIM;

    convert_x<<<dim3(M_TOT * C_DIM / 2048), 256, 0, stream>>>(x, xb);
    transp_w <<<dim3(16, 64), 256, 0, stream>>>(Wq, Wk, Wv, Wp, wt, wpt);
    qkv_gemm <<<dim3(M_TOT / 128, 3 * C_DIM / 128), 256, 0, stream>>>(xb, wt, qb, kb, vtb);
    attn_mfma<<<dim3(BH_N, T_SEQ / 128), 256, 0, stream>>>(qb, kb, vtb, attb);
    proj_gemm<<<dim3(M_TOT / 128, C_DIM / 64), 256, 0, stream>>>(attb, wpt, bp, out);
}